// Round 3
// baseline (702.422 us; speedup 1.0000x reference)
//
#include <hip/hip_runtime.h>
#include <math.h>

#define Hd 192
#define Wd 640
#define HWp (Hd * Wd)
#define NCLS 3
#define KTOP 50
#define NB 32
#define NPL (NB * NCLS)   // 96 planes
#define GPR 160           // 4-pixel groups per row
#define GPP (HWp / 4)     // 30720 groups per plane
#define SEGBLK 120        // scan blocks per plane (256 groups = 1024 px each)
#define SEGCAP 32         // candidate slots per scan block (E~5, >12 sigma)
#define CAP 2048          // per-plane candidate cap for ranking
#define PI_F 3.14159265358979f

// ---------------------------------------------------------------------------
// Peak test for one 4-pixel group. ALL NAMED SCALARS — no arrays, so nothing
// can be demoted to scratch (R1/R2's VGPR_Count=20 showed the float r[3][10]
// array lived in scratch memory, which was the real latency bottleneck).
// 3x3 -inf-padded max-pool semantics identical to jax reduce_window.
// ---------------------------------------------------------------------------
template <typename F>
__device__ inline void peaks_in_group(const float* __restrict__ p, int g, F&& f) {
  const int y = g / GPR;
  const int x0 = (g - y * GPR) * 4;
  const float* rm = p + y * Wd + x0;
  const float4 mq = *(const float4*)rm;
  const float ml = (x0 > 0) ? rm[-1] : -INFINITY;
  const float mr = (x0 + 4 < Wd) ? rm[4] : -INFINITY;
  float4 tq; float tl, tr;
  if (y > 0) {
    const float* rt = rm - Wd;
    tq = *(const float4*)rt;
    tl = (x0 > 0) ? rt[-1] : -INFINITY;
    tr = (x0 + 4 < Wd) ? rt[4] : -INFINITY;
  } else {
    tq.x = tq.y = tq.z = tq.w = -INFINITY; tl = -INFINITY; tr = -INFINITY;
  }
  float4 bq; float bl, br;
  if (y < Hd - 1) {
    const float* rb = rm + Wd;
    bq = *(const float4*)rb;
    bl = (x0 > 0) ? rb[-1] : -INFINITY;
    br = (x0 + 4 < Wd) ? rb[4] : -INFINITY;
  } else {
    bq.x = bq.y = bq.z = bq.w = -INFINITY; bl = -INFINITY; br = -INFINITY;
  }
  const float c0 = fmaxf(fmaxf(tl, ml), bl);
  const float c1 = fmaxf(fmaxf(tq.x, mq.x), bq.x);
  const float c2 = fmaxf(fmaxf(tq.y, mq.y), bq.y);
  const float c3 = fmaxf(fmaxf(tq.z, mq.z), bq.z);
  const float c4 = fmaxf(fmaxf(tq.w, mq.w), bq.w);
  const float c5 = fmaxf(fmaxf(tr, mr), br);
  const int base = y * Wd + x0;
  if (mq.x == fmaxf(fmaxf(c0, c1), c2)) f(__float_as_uint(mq.x), base + 0);
  if (mq.y == fmaxf(fmaxf(c1, c2), c3)) f(__float_as_uint(mq.y), base + 1);
  if (mq.z == fmaxf(fmaxf(c2, c3), c4)) f(__float_as_uint(mq.z), base + 2);
  if (mq.w == fmaxf(fmaxf(c3, c4), c5)) f(__float_as_uint(mq.w), base + 3);
}

template <typename F>
__device__ inline void for_each_peak_plane(const float* __restrict__ p, int tid,
                                           int nth, F&& f) {
  for (int g = tid; g < GPP; g += nth) peaks_in_group(p, g, f);
}

// ---------------------------------------------------------------------------
// Kernel 1: scan. 96 planes x 120 blocks x 256 threads, one 4-px group per
// thread. Candidates (peak AND v >= 0.995) collected via LDS atomic only;
// written to a FIXED per-block global segment + plain count store — zero
// global atomics (R2's per-plane device atomics cost ~60us in XCD ping-pong).
// ---------------------------------------------------------------------------
__global__ __launch_bounds__(256) void scan_kernel(
    const float* __restrict__ heat,
    int* __restrict__ counts,          // [NPL*SEGBLK]
    unsigned int* __restrict__ segbits,// [NPL*SEGBLK][SEGCAP]
    int* __restrict__ segidx) {        // [NPL*SEGBLK][SEGCAP]
  const int blk = blockIdx.x;
  const int plane = blk / SEGBLK;
  const int sub = blk - plane * SEGBLK;
  __shared__ unsigned int s_bits[SEGCAP];
  __shared__ int s_idx[SEGCAP];
  __shared__ int s_n;
  if (threadIdx.x == 0) s_n = 0;
  __syncthreads();

  const float* p = heat + (size_t)plane * HWp;
  const int g = sub * 256 + threadIdx.x;
  const unsigned int TB = __float_as_uint(0.995f);
  peaks_in_group(p, g, [&](unsigned int bits, int idx) {
    if (bits >= TB) {
      int slot = atomicAdd(&s_n, 1);
      if (slot < SEGCAP) { s_bits[slot] = bits; s_idx[slot] = idx; }
    }
  });
  __syncthreads();
  const int n = s_n;
  if (threadIdx.x == 0) counts[blk] = n;  // unclamped: overflow detectable
  const int nn = n < SEGCAP ? n : SEGCAP;
  if (threadIdx.x < nn) {
    segbits[(size_t)blk * SEGCAP + threadIdx.x] = s_bits[threadIdx.x];
    segidx[(size_t)blk * SEGCAP + threadIdx.x] = s_idx[threadIdx.x];
  }
}

// ---------------------------------------------------------------------------
// Kernel 2: fused per-class rank + per-batch rank + 3D decode.
// 32 blocks (one per batch) x 256 threads.
// ---------------------------------------------------------------------------
__device__ inline void inv3(const float* m, float* o) {
  float a = m[0], b = m[1], c = m[2];
  float d = m[3], e = m[4], f = m[5];
  float g = m[6], h = m[7], i = m[8];
  float A = e * i - f * h;
  float B = -(d * i - f * g);
  float C = d * h - e * g;
  float det = a * A + b * B + c * C;
  float id = 1.0f / det;
  o[0] = A * id;            o[1] = -(b * i - c * h) * id; o[2] = (b * f - c * e) * id;
  o[3] = B * id;            o[4] = (a * i - c * g) * id;  o[5] = -(a * f - c * d) * id;
  o[6] = C * id;            o[7] = -(a * h - b * g) * id; o[8] = (a * e - b * d) * id;
}

__device__ inline float wrap_pi(float a) {
  if (a > PI_F) return a - 2.0f * PI_F;
  if (a < -PI_F) return a + 2.0f * PI_F;
  return a;
}

__constant__ float DIM_REF_C[9] = {3.88f, 1.63f, 1.53f,
                                   0.84f, 1.76f, 0.66f,
                                   1.78f, 1.52f, 1.78f};

__global__ __launch_bounds__(256) void rank_decode_kernel(
    const float* __restrict__ heat,
    const int* __restrict__ counts,
    const unsigned int* __restrict__ segbits,
    const int* __restrict__ segidx,
    const float* __restrict__ regr,      // [B][8][HWp]
    const float* __restrict__ trans_mat, // [B][3][3]
    const float* __restrict__ K_mat,     // [B][3][3]
    const float* __restrict__ img_size,  // [B][2]
    float* __restrict__ out) {           // [B*50][14]
  const int b = blockIdx.x;
  const int tid = threadIdx.x;

  __shared__ unsigned int s_bits[CAP];
  __shared__ int s_idx[CAP];
  __shared__ int s_off[SEGBLK + 1];
  __shared__ unsigned int hist[1024];
  __shared__ float cls_sc[NCLS * KTOP];
  __shared__ int cls_pi[NCLS * KTOP];
  __shared__ int sel[KTOP];
  __shared__ int s_flag, s_cnt, s_B, s_above, s_T;

  for (int c = 0; c < NCLS; ++c) {
    const int plane = b * NCLS + c;
    __syncthreads();  // protect s_bits/s_idx reuse across classes
    if (tid == 0) { s_flag = 0; s_off[0] = 0; }
    __syncthreads();
    if (tid < SEGBLK) {
      int n = counts[plane * SEGBLK + tid];
      if (n > SEGCAP) { atomicOr(&s_flag, 1); n = SEGCAP; }
      s_off[tid + 1] = n;
    }
    __syncthreads();
    if (tid == 0) {
      int acc = 0;
      for (int i = 1; i <= SEGBLK; ++i) { acc += s_off[i]; s_off[i] = acc; }
    }
    __syncthreads();
    int M = s_off[SEGBLK];
    const bool fast = (s_flag == 0) && (M >= KTOP) && (M <= CAP);

    if (fast) {
      if (tid < SEGBLK) {
        const int o = s_off[tid];
        const int n = s_off[tid + 1] - o;
        const unsigned int* sb = segbits + (size_t)(plane * SEGBLK + tid) * SEGCAP;
        const int* si = segidx + (size_t)(plane * SEGBLK + tid) * SEGCAP;
        for (int i = 0; i < n; ++i) { s_bits[o + i] = sb[i]; s_idx[o + i] = si[i]; }
      }
      __syncthreads();
    } else {
      // Exact radix-select rescan over float bit patterns (values >= 0).
      // Never triggers on this data; kept for robustness.
      const float* p = heat + (size_t)plane * HWp;
      for (int i = tid; i < 1024; i += 256) hist[i] = 0;
      __syncthreads();
      for_each_peak_plane(p, tid, 256, [&](unsigned int bits, int idx) {
        unsigned int bkt = bits >> 20; if (bkt > 1023u) bkt = 1023u;
        atomicAdd(&hist[bkt], 1u);
      });
      __syncthreads();
      if (tid == 0) {
        int acc = 0, Bs = -1;
        for (int bkt = 1023; bkt >= 0; --bkt) {
          int cc = (int)hist[bkt];
          if (acc + cc >= KTOP) { Bs = bkt; s_above = acc; break; }
          acc += cc;
        }
        s_B = Bs;
        if (Bs < 0) s_above = acc;
      }
      __syncthreads();
      const int Bs = s_B;
      unsigned int T;
      if (Bs < 0) {
        T = 0;  // fewer than 50 peaks total: take them all
      } else {
        for (int i = tid; i < 1024; i += 256) hist[i] = 0;
        __syncthreads();
        for_each_peak_plane(p, tid, 256, [&](unsigned int bits, int idx) {
          unsigned int bkt = bits >> 20; if (bkt > 1023u) bkt = 1023u;
          if ((int)bkt == Bs) atomicAdd(&hist[(bits >> 10) & 1023], 1u);
        });
        __syncthreads();
        if (tid == 0) {
          int acc = s_above, Ss = 0;
          for (int sb = 1023; sb >= 0; --sb) {
            int cc = (int)hist[sb];
            if (acc + cc >= KTOP) { Ss = sb; break; }
            acc += cc;
          }
          s_T = (int)(((unsigned int)Bs << 20) | ((unsigned int)Ss << 10));
        }
        __syncthreads();
        T = (unsigned int)s_T;
      }
      if (tid == 0) s_cnt = 0;
      __syncthreads();
      for_each_peak_plane(p, tid, 256, [&](unsigned int bits, int idx) {
        if (bits >= T) {
          int slot = atomicAdd(&s_cnt, 1);
          if (slot < CAP) { s_bits[slot] = bits; s_idx[slot] = idx; }
        }
      });
      __syncthreads();
      M = s_cnt < CAP ? s_cnt : CAP;
    }

    // Exact rank by (value desc, index asc) == jax.lax.top_k stable order.
    for (int i = tid; i < M; i += 256) {
      const unsigned int vb = s_bits[i];
      const int vi = s_idx[i];
      int rank = 0;
      for (int j = 0; j < M; ++j) {
        const unsigned int wb = s_bits[j];
        rank += (wb > vb) || (wb == vb && s_idx[j] < vi);
      }
      if (rank < KTOP) {
        cls_sc[c * KTOP + rank] = __uint_as_float(vb);
        cls_pi[c * KTOP + rank] = vi;
      }
    }
    for (int s2 = M + tid; s2 < KTOP; s2 += 256) {
      cls_sc[c * KTOP + s2] = 0.0f;
      cls_pi[c * KTOP + s2] = 0;
    }
  }
  __syncthreads();

  // Batch-level top-50 over the 150 class scores (tie: lower position wins).
  if (tid < NCLS * KTOP) {
    const float v = cls_sc[tid];
    int rank = 0;
    for (int j = 0; j < NCLS * KTOP; ++j) {
      const float w = cls_sc[j];
      rank += (w > v) || (w == v && j < tid);
    }
    if (rank < KTOP) sel[rank] = tid;
  }
  __syncthreads();

  if (tid < KTOP) {
    const int i = sel[tid];
    const int cls = i / KTOP;
    const float score = cls_sc[i];
    const int ind = cls_pi[i];
    const float ys = (float)(ind / Wd);
    const float xs = (float)(ind - (ind / Wd) * Wd);

    const float* rb = regr + (size_t)b * 8 * HWp + ind;
    const float r0 = rb[0 * HWp], r1 = rb[1 * HWp], r2 = rb[2 * HWp], r3 = rb[3 * HWp];
    const float r4 = rb[4 * HWp], r5 = rb[5 * HWp], r6 = rb[6 * HWp], r7 = rb[7 * HWp];

    float tm[9], km[9], tmi[9], kmi[9];
#pragma unroll
    for (int q = 0; q < 9; ++q) { tm[q] = trans_mat[b * 9 + q]; km[q] = K_mat[b * 9 + q]; }
    inv3(tm, tmi);
    inv3(km, kmi);

    const float px = xs + r1, py = ys + r2;
    const float gx = tmi[0] * px + tmi[1] * py + tmi[2];
    const float gy = tmi[3] * px + tmi[4] * py + tmi[5];
    const float gz = tmi[6] * px + tmi[7] * py + tmi[8];
    const float depth = r0 * 16.32f + 28.01f;
    const float qx = gx * depth, qy = gy * depth, qz = gz * depth;
    const float lx = kmi[0] * qx + kmi[1] * qy + kmi[2] * qz;
    float ly = kmi[3] * qx + kmi[4] * qy + kmi[5] * qz;
    const float lz = kmi[6] * qx + kmi[7] * qy + kmi[8] * qz;

    const float d0 = expf(r3) * DIM_REF_C[cls * 3 + 0];
    const float d1 = expf(r4) * DIM_REF_C[cls * 3 + 1];
    const float d2 = expf(r5) * DIM_REF_C[cls * 3 + 2];
    ly += d1 * 0.5f;

    const float ray = atanf(lx / (lz + 1e-7f));
    float alpha = atanf(r6 / (r7 + 1e-7f));
    alpha += (r7 >= 0.0f) ? -PI_F * 0.5f : PI_F * 0.5f;
    const float roty = wrap_pi(alpha + ray);
    alpha = wrap_pi(alpha);

    const float SX[8] = {-0.5f, 0.5f, 0.5f, 0.5f, 0.5f, -0.5f, -0.5f, -0.5f};
    const float SY[8] = {-1.0f, -1.0f, 0.0f, 0.0f, -1.0f, -1.0f, 0.0f, 0.0f};
    const float SZ[8] = {-0.5f, -0.5f, -0.5f, 0.5f, 0.5f, 0.5f, 0.5f, -0.5f};
    const float cr = cosf(roty), sr = sinf(roty);
    float minx = INFINITY, maxx = -INFINITY, miny = INFINITY, maxy = -INFINITY;
#pragma unroll
    for (int j = 0; j < 8; ++j) {
      const float ax = d0 * SX[j], ay = d1 * SY[j], az = d2 * SZ[j];
      const float cx = cr * ax + sr * az + lx;
      const float cy = ay + ly;
      const float cz = -sr * ax + cr * az + lz;
      const float ppx = km[0] * cx + km[1] * cy + km[2] * cz;
      const float ppy = km[3] * cx + km[4] * cy + km[5] * cz;
      const float ppz = km[6] * cx + km[7] * cy + km[8] * cz;
      const float X = ppx / ppz, Y = ppy / ppz;
      minx = fminf(minx, X); maxx = fmaxf(maxx, X);
      miny = fminf(miny, Y); maxy = fmaxf(maxy, Y);
    }
    const float Wi = img_size[b * 2 + 0], Hi = img_size[b * 2 + 1];
    const float xmin = fminf(fmaxf(minx, 0.0f), Wi);
    const float ymin = fminf(fmaxf(miny, 0.0f), Hi);
    const float xmax = fminf(fmaxf(maxx, 0.0f), Wi);
    const float ymax = fminf(fmaxf(maxy, 0.0f), Hi);

    float* o = out + (size_t)(b * KTOP + tid) * 14;
    if (score > 0.25f) {
      o[0] = (float)cls; o[1] = alpha;
      o[2] = xmin; o[3] = ymin; o[4] = xmax; o[5] = ymax;
      o[6] = d1; o[7] = d2; o[8] = d0;   // dims rolled by -1
      o[9] = lx; o[10] = ly; o[11] = lz;
      o[12] = roty; o[13] = score;
    } else {
#pragma unroll
      for (int q = 0; q < 14; ++q) o[q] = 0.0f;
    }
  }
}

// ---------------------------------------------------------------------------

extern "C" void kernel_launch(void* const* d_in, const int* in_sizes, int n_in,
                              void* d_out, int out_size, void* d_ws, size_t ws_size,
                              hipStream_t stream) {
  const float* heat = (const float*)d_in[0];  // [32,3,192,640]
  const float* regr = (const float*)d_in[1];  // [32,8,192,640]
  const float* tmat = (const float*)d_in[2];  // [32,3,3]
  const float* kmat = (const float*)d_in[3];  // [32,3,3]
  const float* isz = (const float*)d_in[4];   // [32,2]

  // Workspace layout (512B-aligned): ~3.0 MB total.
  char* ws = (char*)d_ws;
  int* counts = (int*)ws;                                   // 11520*4 = 46080 B
  unsigned int* segbits = (unsigned int*)(ws + 46080);      // 11520*32*4 B
  int* segidx = (int*)(ws + 46080 + (size_t)NPL * SEGBLK * SEGCAP * 4);

  scan_kernel<<<NPL * SEGBLK, 256, 0, stream>>>(heat, counts, segbits, segidx);
  rank_decode_kernel<<<NB, 256, 0, stream>>>(heat, counts, segbits, segidx,
                                             regr, tmat, kmat, isz, (float*)d_out);
}

// Round 4
// 226.641 us; speedup vs baseline: 3.0993x; 3.0993x over previous
//
#include <hip/hip_runtime.h>
#include <math.h>

#define Hd 192
#define Wd 640
#define HWp (Hd * Wd)
#define NCLS 3
#define KTOP 50
#define NB 32
#define NPL (NB * NCLS)   // 96 planes
#define GPR 160           // 4-pixel groups per row
#define GPP (HWp / 4)     // 30720 groups per plane
#define SEGBLK 120        // scan blocks per plane (256 groups = 1024 px each)
#define SEGCAP 32         // candidate slots per scan block (E~5, >12 sigma)
#define CAP 2048          // per-plane candidate cap for ranking
#define RBK 256           // rank buckets
#define PI_F 3.14159265358979f

// ---------------------------------------------------------------------------
// Peak test for one 4-pixel group. All named scalars — nothing demotable to
// scratch. 3x3 -inf-padded max-pool semantics identical to jax reduce_window.
// ---------------------------------------------------------------------------
template <typename F>
__device__ inline void peaks_in_group(const float* __restrict__ p, int g, F&& f) {
  const int y = g / GPR;
  const int x0 = (g - y * GPR) * 4;
  const float* rm = p + y * Wd + x0;
  const float4 mq = *(const float4*)rm;
  const float ml = (x0 > 0) ? rm[-1] : -INFINITY;
  const float mr = (x0 + 4 < Wd) ? rm[4] : -INFINITY;
  float4 tq; float tl, tr;
  if (y > 0) {
    const float* rt = rm - Wd;
    tq = *(const float4*)rt;
    tl = (x0 > 0) ? rt[-1] : -INFINITY;
    tr = (x0 + 4 < Wd) ? rt[4] : -INFINITY;
  } else {
    tq.x = tq.y = tq.z = tq.w = -INFINITY; tl = -INFINITY; tr = -INFINITY;
  }
  float4 bq; float bl, br;
  if (y < Hd - 1) {
    const float* rb = rm + Wd;
    bq = *(const float4*)rb;
    bl = (x0 > 0) ? rb[-1] : -INFINITY;
    br = (x0 + 4 < Wd) ? rb[4] : -INFINITY;
  } else {
    bq.x = bq.y = bq.z = bq.w = -INFINITY; bl = -INFINITY; br = -INFINITY;
  }
  const float c0 = fmaxf(fmaxf(tl, ml), bl);
  const float c1 = fmaxf(fmaxf(tq.x, mq.x), bq.x);
  const float c2 = fmaxf(fmaxf(tq.y, mq.y), bq.y);
  const float c3 = fmaxf(fmaxf(tq.z, mq.z), bq.z);
  const float c4 = fmaxf(fmaxf(tq.w, mq.w), bq.w);
  const float c5 = fmaxf(fmaxf(tr, mr), br);
  const int base = y * Wd + x0;
  if (mq.x == fmaxf(fmaxf(c0, c1), c2)) f(__float_as_uint(mq.x), base + 0);
  if (mq.y == fmaxf(fmaxf(c1, c2), c3)) f(__float_as_uint(mq.y), base + 1);
  if (mq.z == fmaxf(fmaxf(c2, c3), c4)) f(__float_as_uint(mq.z), base + 2);
  if (mq.w == fmaxf(fmaxf(c3, c4), c5)) f(__float_as_uint(mq.w), base + 3);
}

template <typename F>
__device__ inline void for_each_peak_plane(const float* __restrict__ p, int tid,
                                           int nth, F&& f) {
  for (int g = tid; g < GPP; g += nth) peaks_in_group(p, g, f);
}

// key = (bits << 32) | ~idx : strict u64 '>' == (value desc, idx asc).
__device__ inline unsigned long long mk_key(unsigned int bits, int idx) {
  return ((unsigned long long)bits << 32) | (unsigned int)~idx;
}

// Monotone bucket over value bits; uniform for the fast-path range
// [0.995, 1.0) (span 0x147AE >> 9 -> ~164 buckets); clamped elsewhere.
__device__ inline int bucket_of(unsigned int bits) {
  const unsigned int base = __float_as_uint(0.995f);
  if (bits <= base) return 0;
  unsigned int d = (bits - base) >> 9;
  return d > 255u ? 255 : (int)d;
}

// ---------------------------------------------------------------------------
// Kernel 1: scan. 96 planes x 120 blocks x 256 threads, one 4-px group per
// thread. LDS atomics only; fixed per-block segment + plain count store.
// ---------------------------------------------------------------------------
__global__ __launch_bounds__(256) void scan_kernel(
    const float* __restrict__ heat,
    int* __restrict__ counts,                 // [NPL*SEGBLK]
    unsigned long long* __restrict__ segkey) {// [NPL*SEGBLK][SEGCAP]
  const int blk = blockIdx.x;
  const int plane = blk / SEGBLK;
  const int sub = blk - plane * SEGBLK;
  __shared__ unsigned long long s_k[SEGCAP];
  __shared__ int s_n;
  if (threadIdx.x == 0) s_n = 0;
  __syncthreads();

  const float* p = heat + (size_t)plane * HWp;
  const int g = sub * 256 + threadIdx.x;
  const unsigned int TB = __float_as_uint(0.995f);
  peaks_in_group(p, g, [&](unsigned int bits, int idx) {
    if (bits >= TB) {
      int slot = atomicAdd(&s_n, 1);
      if (slot < SEGCAP) s_k[slot] = mk_key(bits, idx);
    }
  });
  __syncthreads();
  const int n = s_n;
  if (threadIdx.x == 0) counts[blk] = n;  // unclamped: overflow detectable
  const int nn = n < SEGCAP ? n : SEGCAP;
  if (threadIdx.x < nn)
    segkey[(size_t)blk * SEGCAP + threadIdx.x] = s_k[threadIdx.x];
}

// ---------------------------------------------------------------------------
// Kernel 2: fused per-class counting-sort rank (O(M)) + batch rank + decode.
// 32 blocks (one per batch) x 256 threads.
// ---------------------------------------------------------------------------
__device__ inline void inv3(const float* m, float* o) {
  float a = m[0], b = m[1], c = m[2];
  float d = m[3], e = m[4], f = m[5];
  float g = m[6], h = m[7], i = m[8];
  float A = e * i - f * h;
  float B = -(d * i - f * g);
  float C = d * h - e * g;
  float det = a * A + b * B + c * C;
  float id = 1.0f / det;
  o[0] = A * id;            o[1] = -(b * i - c * h) * id; o[2] = (b * f - c * e) * id;
  o[3] = B * id;            o[4] = (a * i - c * g) * id;  o[5] = -(a * f - c * d) * id;
  o[6] = C * id;            o[7] = -(a * h - b * g) * id; o[8] = (a * e - b * d) * id;
}

__device__ inline float wrap_pi(float a) {
  if (a > PI_F) return a - 2.0f * PI_F;
  if (a < -PI_F) return a + 2.0f * PI_F;
  return a;
}

__constant__ float DIM_REF_C[9] = {3.88f, 1.63f, 1.53f,
                                   0.84f, 1.76f, 0.66f,
                                   1.78f, 1.52f, 1.78f};

__global__ __launch_bounds__(256) void rank_decode_kernel(
    const float* __restrict__ heat,
    const int* __restrict__ counts,
    const unsigned long long* __restrict__ segkey,
    const float* __restrict__ regr,      // [B][8][HWp]
    const float* __restrict__ trans_mat, // [B][3][3]
    const float* __restrict__ K_mat,     // [B][3][3]
    const float* __restrict__ img_size,  // [B][2]
    float* __restrict__ out) {           // [B*50][14]
  const int b = blockIdx.x;
  const int tid = threadIdx.x;

  __shared__ unsigned long long s_key[CAP];   // raw candidates
  __shared__ unsigned long long g_key[CAP];   // bucket-grouped
  __shared__ int s_off[SEGBLK + 1];
  __shared__ int cnt[RBK], suf[RBK], cur[RBK];
  __shared__ unsigned int fb_hist[1024];
  __shared__ float cls_sc[NCLS * KTOP];
  __shared__ int cls_pi[NCLS * KTOP];
  __shared__ int sel[KTOP];
  __shared__ int s_flag, s_cnt, s_B, s_above, s_T;

  for (int c = 0; c < NCLS; ++c) {
    const int plane = b * NCLS + c;
    __syncthreads();  // protect s_key/g_key reuse across classes
    if (tid == 0) { s_flag = 0; s_off[0] = 0; }
    __syncthreads();
    if (tid < SEGBLK) {
      int n = counts[plane * SEGBLK + tid];
      if (n > SEGCAP) { atomicOr(&s_flag, 1); n = SEGCAP; }
      s_off[tid + 1] = n;
    }
    __syncthreads();
    if (tid == 0) {
      int acc = 0;
      for (int i = 1; i <= SEGBLK; ++i) { acc += s_off[i]; s_off[i] = acc; }
    }
    __syncthreads();
    int M = s_off[SEGBLK];
    const bool fast = (s_flag == 0) && (M >= KTOP) && (M <= CAP);

    if (fast) {
      if (tid < SEGBLK) {
        const int o = s_off[tid];
        const int n = s_off[tid + 1] - o;
        const unsigned long long* sk = segkey + (size_t)(plane * SEGBLK + tid) * SEGCAP;
        for (int i = 0; i < n; ++i) s_key[o + i] = sk[i];
      }
      __syncthreads();
    } else {
      // Exact radix-select rescan (values >= 0); never triggers on this data.
      const float* p = heat + (size_t)plane * HWp;
      for (int i = tid; i < 1024; i += 256) fb_hist[i] = 0;
      __syncthreads();
      for_each_peak_plane(p, tid, 256, [&](unsigned int bits, int idx) {
        unsigned int bkt = bits >> 20; if (bkt > 1023u) bkt = 1023u;
        atomicAdd(&fb_hist[bkt], 1u);
      });
      __syncthreads();
      if (tid == 0) {
        int acc = 0, Bs = -1;
        for (int bkt = 1023; bkt >= 0; --bkt) {
          int cc = (int)fb_hist[bkt];
          if (acc + cc >= KTOP) { Bs = bkt; s_above = acc; break; }
          acc += cc;
        }
        s_B = Bs;
        if (Bs < 0) s_above = acc;
      }
      __syncthreads();
      const int Bs = s_B;
      unsigned int T;
      if (Bs < 0) {
        T = 0;  // fewer than 50 peaks total: take them all
      } else {
        for (int i = tid; i < 1024; i += 256) fb_hist[i] = 0;
        __syncthreads();
        for_each_peak_plane(p, tid, 256, [&](unsigned int bits, int idx) {
          unsigned int bkt = bits >> 20; if (bkt > 1023u) bkt = 1023u;
          if ((int)bkt == Bs) atomicAdd(&fb_hist[(bits >> 10) & 1023], 1u);
        });
        __syncthreads();
        if (tid == 0) {
          int acc = s_above, Ss = 0;
          for (int sb = 1023; sb >= 0; --sb) {
            int cc = (int)fb_hist[sb];
            if (acc + cc >= KTOP) { Ss = sb; break; }
            acc += cc;
          }
          s_T = (int)(((unsigned int)Bs << 20) | ((unsigned int)Ss << 10));
        }
        __syncthreads();
        T = (unsigned int)s_T;
      }
      if (tid == 0) s_cnt = 0;
      __syncthreads();
      for_each_peak_plane(p, tid, 256, [&](unsigned int bits, int idx) {
        if (bits >= T) {
          int slot = atomicAdd(&s_cnt, 1);
          if (slot < CAP) s_key[slot] = mk_key(bits, idx);
        }
      });
      __syncthreads();
      M = s_cnt < CAP ? s_cnt : CAP;
    }

    // ---- O(M) counting-sort rank: exact (value desc, idx asc) order. ----
    for (int i = tid; i < RBK; i += 256) { cnt[i] = 0; cur[i] = 0; }
    __syncthreads();
    for (int i = tid; i < M; i += 256)
      atomicAdd(&cnt[bucket_of((unsigned int)(s_key[i] >> 32))], 1);
    __syncthreads();
    if (tid == 0) {
      int acc = 0;
      for (int bq = RBK - 1; bq >= 0; --bq) { suf[bq] = acc; acc += cnt[bq]; }
    }
    __syncthreads();
    for (int i = tid; i < M; i += 256) {
      const unsigned long long k = s_key[i];
      const int bq = bucket_of((unsigned int)(k >> 32));
      const int slot = suf[bq] + atomicAdd(&cur[bq], 1);
      g_key[slot] = k;
    }
    __syncthreads();
    for (int i = tid; i < M; i += 256) {
      const unsigned long long k = g_key[i];
      const int bq = bucket_of((unsigned int)(k >> 32));
      const int st = suf[bq];
      const int nb = cnt[bq];
      int rank = st;
      for (int t = st; t < st + nb; ++t) rank += (g_key[t] > k);
      if (rank < KTOP) {
        cls_sc[c * KTOP + rank] = __uint_as_float((unsigned int)(k >> 32));
        cls_pi[c * KTOP + rank] = (int)~((unsigned int)k);
      }
    }
    for (int s2 = M + tid; s2 < KTOP; s2 += 256) {
      cls_sc[c * KTOP + s2] = 0.0f;
      cls_pi[c * KTOP + s2] = 0;
    }
  }
  __syncthreads();

  // Batch-level top-50 over 150 scores (tie: lower flattened position wins).
  if (tid < NCLS * KTOP) {
    const float v = cls_sc[tid];
    int rank = 0;
    for (int j = 0; j < NCLS * KTOP; ++j) {
      const float w = cls_sc[j];
      rank += (w > v) || (w == v && j < tid);
    }
    if (rank < KTOP) sel[rank] = tid;
  }
  __syncthreads();

  if (tid < KTOP) {
    const int i = sel[tid];
    const int cls = i / KTOP;
    const float score = cls_sc[i];
    const int ind = cls_pi[i];
    const float ys = (float)(ind / Wd);
    const float xs = (float)(ind - (ind / Wd) * Wd);

    const float* rb = regr + (size_t)b * 8 * HWp + ind;
    const float r0 = rb[0 * HWp], r1 = rb[1 * HWp], r2 = rb[2 * HWp], r3 = rb[3 * HWp];
    const float r4 = rb[4 * HWp], r5 = rb[5 * HWp], r6 = rb[6 * HWp], r7 = rb[7 * HWp];

    float tm[9], km[9], tmi[9], kmi[9];
#pragma unroll
    for (int q = 0; q < 9; ++q) { tm[q] = trans_mat[b * 9 + q]; km[q] = K_mat[b * 9 + q]; }
    inv3(tm, tmi);
    inv3(km, kmi);

    const float px = xs + r1, py = ys + r2;
    const float gx = tmi[0] * px + tmi[1] * py + tmi[2];
    const float gy = tmi[3] * px + tmi[4] * py + tmi[5];
    const float gz = tmi[6] * px + tmi[7] * py + tmi[8];
    const float depth = r0 * 16.32f + 28.01f;
    const float qx = gx * depth, qy = gy * depth, qz = gz * depth;
    const float lx = kmi[0] * qx + kmi[1] * qy + kmi[2] * qz;
    float ly = kmi[3] * qx + kmi[4] * qy + kmi[5] * qz;
    const float lz = kmi[6] * qx + kmi[7] * qy + kmi[8] * qz;

    const float d0 = expf(r3) * DIM_REF_C[cls * 3 + 0];
    const float d1 = expf(r4) * DIM_REF_C[cls * 3 + 1];
    const float d2 = expf(r5) * DIM_REF_C[cls * 3 + 2];
    ly += d1 * 0.5f;

    const float ray = atanf(lx / (lz + 1e-7f));
    float alpha = atanf(r6 / (r7 + 1e-7f));
    alpha += (r7 >= 0.0f) ? -PI_F * 0.5f : PI_F * 0.5f;
    const float roty = wrap_pi(alpha + ray);
    alpha = wrap_pi(alpha);

    const float SX[8] = {-0.5f, 0.5f, 0.5f, 0.5f, 0.5f, -0.5f, -0.5f, -0.5f};
    const float SY[8] = {-1.0f, -1.0f, 0.0f, 0.0f, -1.0f, -1.0f, 0.0f, 0.0f};
    const float SZ[8] = {-0.5f, -0.5f, -0.5f, 0.5f, 0.5f, 0.5f, 0.5f, -0.5f};
    const float cr = cosf(roty), sr = sinf(roty);
    float minx = INFINITY, maxx = -INFINITY, miny = INFINITY, maxy = -INFINITY;
#pragma unroll
    for (int j = 0; j < 8; ++j) {
      const float ax = d0 * SX[j], ay = d1 * SY[j], az = d2 * SZ[j];
      const float cx = cr * ax + sr * az + lx;
      const float cy = ay + ly;
      const float cz = -sr * ax + cr * az + lz;
      const float ppx = km[0] * cx + km[1] * cy + km[2] * cz;
      const float ppy = km[3] * cx + km[4] * cy + km[5] * cz;
      const float ppz = km[6] * cx + km[7] * cy + km[8] * cz;
      const float X = ppx / ppz, Y = ppy / ppz;
      minx = fminf(minx, X); maxx = fmaxf(maxx, X);
      miny = fminf(miny, Y); maxy = fmaxf(maxy, Y);
    }
    const float Wi = img_size[b * 2 + 0], Hi = img_size[b * 2 + 1];
    const float xmin = fminf(fmaxf(minx, 0.0f), Wi);
    const float ymin = fminf(fmaxf(miny, 0.0f), Hi);
    const float xmax = fminf(fmaxf(maxx, 0.0f), Wi);
    const float ymax = fminf(fmaxf(maxy, 0.0f), Hi);

    float* o = out + (size_t)(b * KTOP + tid) * 14;
    if (score > 0.25f) {
      o[0] = (float)cls; o[1] = alpha;
      o[2] = xmin; o[3] = ymin; o[4] = xmax; o[5] = ymax;
      o[6] = d1; o[7] = d2; o[8] = d0;   // dims rolled by -1
      o[9] = lx; o[10] = ly; o[11] = lz;
      o[12] = roty; o[13] = score;
    } else {
#pragma unroll
      for (int q = 0; q < 14; ++q) o[q] = 0.0f;
    }
  }
}

// ---------------------------------------------------------------------------

extern "C" void kernel_launch(void* const* d_in, const int* in_sizes, int n_in,
                              void* d_out, int out_size, void* d_ws, size_t ws_size,
                              hipStream_t stream) {
  const float* heat = (const float*)d_in[0];  // [32,3,192,640]
  const float* regr = (const float*)d_in[1];  // [32,8,192,640]
  const float* tmat = (const float*)d_in[2];  // [32,3,3]
  const float* kmat = (const float*)d_in[3];  // [32,3,3]
  const float* isz = (const float*)d_in[4];   // [32,2]

  // Workspace: counts (46080 B, 8-aligned) then u64 segments (~2.95 MB).
  char* ws = (char*)d_ws;
  int* counts = (int*)ws;
  unsigned long long* segkey = (unsigned long long*)(ws + 46080);

  scan_kernel<<<NPL * SEGBLK, 256, 0, stream>>>(heat, counts, segkey);
  rank_decode_kernel<<<NB, 256, 0, stream>>>(heat, counts, segkey,
                                             regr, tmat, kmat, isz, (float*)d_out);
}